// Round 11
// baseline (60.875 us; speedup 1.0000x reference)
//
#include <hip/hip_runtime.h>
#include <hip/hip_bf16.h>

typedef int v4i __attribute__((ext_vector_type(4)));
typedef int v16i __attribute__((ext_vector_type(16)));

// Padded quantized activations: qp[n][hp][wp][c], hp,wp in [0,114), c in [0,64)
#define QP_N 32
#define QP_HP 114
#define QP_WP 114
#define QP_C 64
#define QP_ROW (QP_WP * QP_C)                            // 7296 B per padded row
#define QP_BYTES ((size_t)QP_N * QP_HP * QP_WP * QP_C)   // 26,615,808

#define QBLOCKS (QP_N * QP_HP)      // 3648 quantize blocks
#define PBLOCKS 9                   // prepack blocks folded into same launch

// XCD pinning (r7, -3.4us): both kernels remap blockIdx bijectively so every
// block of image n has blockIdx % 8 == n % 8 -> qp producer/consumer share an
// XCD (3.3 MB/XCD < 4 MB L2). NO nontemporal hints (r4-r6: +5-7us poison).

// ---------------------------------------------------------------------------
// Kernel 1: quantize + NCHW -> padded NHWC int8 transpose, with border zeroing.
// Physical blocks [0, 3648): p = ((n>>3)*114 + hp)*8 + (n&7)  (bijective).
// Blocks [3648, 3657): weight prepack into 32x32x32 MFMA B-fragment layout.
//   wb[frag][lane][16B], frag = tap*4 + cih*2 + cog  (tap = kh*3+kw).
//   B-frag (K=32 ci x N=32 co): lane l holds B[k=(l>>5)*16+j][n=l&31], j=0..15.
//   co = cog*32 + (l&31), ci = cih*32 + (l>>5)*16 + j.  qw arrives as int32.
// ---------------------------------------------------------------------------
__global__ __launch_bounds__(256) void quantize_kernel(const float* __restrict__ x,
                                                       signed char* __restrict__ qp,
                                                       const int* __restrict__ qw,
                                                       signed char* __restrict__ wb) {
    int t = threadIdx.x;

    if (blockIdx.x >= QBLOCKS) {
        // ---- prepack path (32x32x32 layout) ----
        int idx = (blockIdx.x - QBLOCKS) * 256 + t;
        if (idx >= 36 * 64) return;
        int lane = idx & 63;
        int frag = idx >> 6;             // 0..35
        int cog = frag & 1;
        int cih = (frag >> 1) & 1;
        int tap = frag >> 2;             // kh*3+kw
        int kh = tap / 3;
        int kw = tap - kh * 3;
        int co = cog * 32 + (lane & 31);
        int cibase = cih * 32 + (lane >> 5) * 16;
        int dwv[4];
#pragma unroll
        for (int d = 0; d < 4; ++d) {
            int acc = 0;
#pragma unroll
            for (int b = 0; b < 4; ++b) {
                int ci = cibase + d * 4 + b;
                int v = qw[((co * 64 + ci) * 3 + kh) * 3 + kw];
                acc |= (v & 0xff) << (8 * b);
            }
            dwv[d] = acc;
        }
        *reinterpret_cast<int4*>(wb + (size_t)idx * 16) = make_int4(dwv[0], dwv[1], dwv[2], dwv[3]);
        return;
    }

    // XCD-pinned index decode: p = ((n>>3)*114 + hp)*8 + (n&7)
    int p = blockIdx.x;
    int res = p & 7;
    int r = p >> 3;                 // 0..455
    int gq = r / 114;               // n>>3 in 0..3
    int hp = r - gq * 114;
    int n = gq * 8 + res;

    signed char* rowbase = qp + ((size_t)n * QP_HP + hp) * QP_ROW;

    if (hp == 0 || hp == QP_HP - 1) {
        // zero the whole padded row: 114*64 = 7296 B = 228 * 32B
        if (t < 228) {
            int4 z = make_int4(0, 0, 0, 0);
            int4* dst = reinterpret_cast<int4*>(rowbase + t * 32);
            dst[0] = z;
            dst[1] = z;
        }
        return;
    }

    int h = hp - 1;
    __shared__ float lds[64][112];

    const float* xp = x + (size_t)n * 64 * 12544 + h * 112;  // x[n][c][h][w], c-plane stride 12544
#pragma unroll
    for (int j = 0; j < 7; ++j) {
        int fidx = j * 256 + t;      // 1792 float4 chunks total (64 rows * 28)
        int c = fidx / 28;
        int f = fidx - c * 28;
        float4 v = *reinterpret_cast<const float4*>(xp + (size_t)c * 12544 + f * 4);
        *reinterpret_cast<float4*>(&lds[c][f * 4]) = v;
    }
    __syncthreads();

    if (t < 224) {
        int w = t >> 1;              // 0..111
        int ch = (t & 1) * 32;       // channel half: 0 or 32
        int dw[8];
#pragma unroll
        for (int q = 0; q < 8; ++q) {
            int d = 0;
#pragma unroll
            for (int b = 0; b < 4; ++b) {
                float v = lds[ch + q * 4 + b][w];
                float s = rintf(v * 20.0f);                 // round-half-to-even, matches jnp.round
                s = fminf(127.0f, fmaxf(-128.0f, s));
                int iv = (int)s;
                d |= (iv & 0xff) << (8 * b);
            }
            dw[q] = d;
        }
        int4* dst = reinterpret_cast<int4*>(rowbase + (size_t)(w + 1) * QP_C + ch);
        dst[0] = make_int4(dw[0], dw[1], dw[2], dw[3]);
        dst[1] = make_int4(dw[4], dw[5], dw[6], dw[7]);
    } else if (t < 232) {
        // zero border columns wp=0 and wp=113 (64 B each = 4 int4 each)
        int i = t - 224;
        int col = (i >> 2) ? (QP_WP - 1) : 0;
        int part = i & 3;
        *reinterpret_cast<int4*>(rowbase + (size_t)col * QP_C + part * 16) = make_int4(0, 0, 0, 0);
    }
}

// ---------------------------------------------------------------------------
// Kernel 2: implicit-GEMM conv on mfma_i32_32x32x32_i8.
// 512-thr blocks = 2 rows x 4 waves; waves at w0 = {0,32,64,80}; the w0=80
// wave recomputes px 80..95 (overlap) and stores only px 96..111 (regs 8..15).
// Per wave: 32 px x 64 co; per tap: 2 A-loads (16B, cih halves), 4 ds_reads,
// 4 MFMAs. Distance-2 A prefetch (af0/af1/af2, ~92 VGPR <= 128 cap) covers
// the ~250cy L2 latency. setprio(1) around MFMA cluster (r10, proven).
//   A-frag: lane l: px = w0+(l&31), k = (l>>5)*16+j, ci = cih*32+k
//   D: co = cog*32 + (l&31); px = (reg&3) + 8*(reg>>2) + 4*(l>>5)
//      -> regs 4q..4q+3 = float4 at px 8q+4*(l>>5)
// ---------------------------------------------------------------------------
__global__ __launch_bounds__(512, 4) void conv_kernel(const signed char* __restrict__ qp,
                                                      const signed char* __restrict__ wb,
                                                      const int* __restrict__ bias,
                                                      const float* __restrict__ deq,
                                                      float* __restrict__ out) {
    __shared__ signed char wlds[36864];
    int t = threadIdx.x;
#pragma unroll
    for (int i = 0; i < 5; ++i) {
        int idx = i * 512 + t;
        if (idx < 2304) {
            *reinterpret_cast<int4*>(&wlds[(size_t)idx * 16]) =
                *reinterpret_cast<const int4*>(wb + (size_t)idx * 16);
        }
    }
    __syncthreads();

    int wave = t >> 6;
    int lane = t & 63;

    // XCD-pinned index decode: p = ((n>>3)*56 + k)*8 + (n&7)
    int p = blockIdx.x;              // 0..1791
    int res = p & 7;
    int s = p >> 3;                  // 0..223
    int gq = s / 56;                 // n>>3 in 0..3
    int k = s - gq * 56;             // 0..55
    int n = gq * 8 + res;

    int h = k * 2 + (wave >> 2);     // output row
    int sub = wave & 3;
    bool tail = (sub == 3);
    int w0 = tail ? 80 : sub * 32;

    const signed char* abase = qp + ((size_t)(n * QP_HP + h) * QP_WP + w0) * QP_C
                             + (lane & 31) * 64 + (lane >> 5) * 16;
    const signed char* wl = wlds + lane * 16;
    float* outp = out + (size_t)n * 64 * 12544 + h * 112 + w0;

    v16i acc0 = {0,0,0,0,0,0,0,0,0,0,0,0,0,0,0,0};
    v16i acc1 = {0,0,0,0,0,0,0,0,0,0,0,0,0,0,0,0};

    // tap byte offsets (kh*QP_ROW + kw*64), taps 0..8
    v4i af0[2], af1[2], af2[2];
#pragma unroll
    for (int c = 0; c < 2; ++c) {
        af0[c] = *reinterpret_cast<const v4i*>(abase + 0 + c * 32);     // tap0: kh0 kw0
        af1[c] = *reinterpret_cast<const v4i*>(abase + 64 + c * 32);    // tap1: kh0 kw1
    }

#pragma unroll
    for (int tt = 0; tt < 9; ++tt) {
        if (tt < 7) {
            const int t2 = tt + 2;
            const int kh2 = t2 / 3;
            const int kw2 = t2 - kh2 * 3;
            const int off2 = kh2 * QP_ROW + kw2 * 64;
#pragma unroll
            for (int c = 0; c < 2; ++c)
                af2[c] = *reinterpret_cast<const v4i*>(abase + off2 + c * 32);
        }
        v4i wf00 = *reinterpret_cast<const v4i*>(wl + (size_t)(tt * 4 + 0) * 1024); // cih0 cog0
        v4i wf01 = *reinterpret_cast<const v4i*>(wl + (size_t)(tt * 4 + 1) * 1024); // cih0 cog1
        v4i wf10 = *reinterpret_cast<const v4i*>(wl + (size_t)(tt * 4 + 2) * 1024); // cih1 cog0
        v4i wf11 = *reinterpret_cast<const v4i*>(wl + (size_t)(tt * 4 + 3) * 1024); // cih1 cog1
        __builtin_amdgcn_s_setprio(1);
        acc0 = __builtin_amdgcn_mfma_i32_32x32x32_i8(af0[0], wf00, acc0, 0, 0, 0);
        acc1 = __builtin_amdgcn_mfma_i32_32x32x32_i8(af0[0], wf01, acc1, 0, 0, 0);
        acc0 = __builtin_amdgcn_mfma_i32_32x32x32_i8(af0[1], wf10, acc0, 0, 0, 0);
        acc1 = __builtin_amdgcn_mfma_i32_32x32x32_i8(af0[1], wf11, acc1, 0, 0, 0);
        __builtin_amdgcn_s_setprio(0);
        if (tt < 7) {
#pragma unroll
            for (int c = 0; c < 2; ++c) { af0[c] = af1[c]; af1[c] = af2[c]; }
        } else if (tt == 7) {
#pragma unroll
            for (int c = 0; c < 2; ++c) { af0[c] = af1[c]; }
        }
    }

    int co_l = lane & 31;
    int hi4 = (lane >> 5) * 4;
#pragma unroll
    for (int cog = 0; cog < 2; ++cog) {
        v16i ac = cog ? acc1 : acc0;
        int co = cog * 32 + co_l;
        int bv = bias[co];
        float dv = deq[co];
        float* orow = outp + (size_t)co * 12544 + hi4;
#pragma unroll
        for (int q = 0; q < 4; ++q) {
            if (tail && q < 2) continue;     // tail wave stores only px 96..111
            float4 v;
            v.x = (float)(ac[q * 4 + 0] + bv) * dv;
            v.y = (float)(ac[q * 4 + 1] + bv) * dv;
            v.z = (float)(ac[q * 4 + 2] + bv) * dv;
            v.w = (float)(ac[q * 4 + 3] + bv) * dv;
            *reinterpret_cast<float4*>(orow + q * 8) = v;
        }
    }
}

extern "C" void kernel_launch(void* const* d_in, const int* in_sizes, int n_in,
                              void* d_out, int out_size, void* d_ws, size_t ws_size,
                              hipStream_t stream) {
    const float* x   = (const float*)d_in[0];
    const int*   qw  = (const int*)d_in[1];    // int8 values widened to int32
    const int*   bias = (const int*)d_in[2];
    const float* deq = (const float*)d_in[3];
    float* out = (float*)d_out;

    signed char* qp = (signed char*)d_ws;
    signed char* wb = qp + QP_BYTES;

    quantize_kernel<<<QBLOCKS + PBLOCKS, 256, 0, stream>>>(x, qp, qw, wb);
    conv_kernel<<<1792, 512, 0, stream>>>(qp, wb, bias, deq, out);
}